// Round 3
// baseline (372.344 us; speedup 1.0000x reference)
//
#include <hip/hip_runtime.h>

// VectorQuantizer: x [32768, 256] fp32, codebook [1024, 256] fp32.
// Reference (recomputed by harness in float32):
//   d[n,k] = fl( fl( ||x_n||^2 - 2*dot(x_n,c_k) ) + ||c_k||^2 )   (all fp32)
//   idx = argmin_k (first min), out = codebook[idx]
// The fp32 final roundings happen at scale ~300 (ulp ~3e-5) and decide ties;
// exact/fp64 argmin provably mismatches on ~1-2 of 32768 rows (R1/R2 evidence:
// identical absmax with and without fp64 rescore). So we REPLICATE the fp32
// arithmetic:
//  - dot: single sequential fp32 FMA chain over d ascending (== BLAS sgemm
//    microkernel accumulation order; v_fmac_f32, no reassociation at -O3).
//  - q = (S - 2*acc) + cn in fp32: two roundings, same as np's left-to-right.
//  - S = ||x||^2 bits don't matter (grid-multiple shift commutes with
//    rounding -> argmin invariant); fp64-sum -> fp32.
//  - ties resolve to smallest k (np.argmin first-index).

#define D         256
#define K_TOTAL   1024
#define N_ROWS    32768
#define TM        64          // n-rows per block
#define TN        64          // k per chunk
#define NCHUNK    (K_TOTAL / TN)
#define CS_STRIDE 260         // 256 + 4 pad: rows 16B-aligned, <=2-way bank (free)

// ---------------- kernel 1: row norms for x and codebook ----------------
// One wave per row. Elementwise fp32 squares (matching np's flat*flat in
// float32), accumulated in fp64, rounded once to fp32.
__global__ void norms_kernel(const float* __restrict__ x, const float* __restrict__ cb,
                             float* __restrict__ xnorm, float* __restrict__ cnorm) {
    const int wave = threadIdx.x >> 6;          // 0..3
    const int lane = threadIdx.x & 63;
    const int row  = blockIdx.x * 4 + wave;     // 0 .. 33791

    const float* src;
    float* dst;
    int idx;
    if (row < N_ROWS) { src = x  + (size_t)row * D;             dst = xnorm; idx = row; }
    else              { src = cb + (size_t)(row - N_ROWS) * D;  dst = cnorm; idx = row - N_ROWS; }

    float4 v = *(const float4*)(src + lane * 4);
    float sx = v.x * v.x;   // fp32 square (matches np elementwise fp32 mul)
    float sy = v.y * v.y;
    float sz = v.z * v.z;
    float sw = v.w * v.w;
    double s = (double)sx + (double)sy + (double)sz + (double)sw;
    #pragma unroll
    for (int off = 32; off > 0; off >>= 1)
        s += __shfl_down(s, off, 64);
    if (lane == 0) dst[idx] = (float)s;         // single fp64->fp32 rounding
}

// ---------------- kernel 2: fused fp32-replica distance + argmin + gather ----------------
__global__ __launch_bounds__(256, 2)
void vq_kernel(const float* __restrict__ x, const float* __restrict__ cb,
               const float* __restrict__ xnorm, const float* __restrict__ cnorm,
               float* __restrict__ out) {
    __shared__ float cs[TN * CS_STRIDE];     // 66560 B codebook chunk [64 k][256 d]
    __shared__ float red_val[TM * 16];
    __shared__ int   red_idx[TM * 16];
    __shared__ int   best_idx[TM];

    const int tid = threadIdx.x;
    const int tx  = tid & 15;                // k-group owner (k = tx + 16j)
    const int ty  = tid >> 4;                // n-group owner (n = ty + 16i)
    const int n0  = blockIdx.x * TM;

    float runmin[4];
    int   runidx[4];
    float S[4];
    const float* xrow[4];
    #pragma unroll
    for (int i = 0; i < 4; ++i) {
        runmin[i] = 1e30f; runidx[i] = 0;
        const int n = n0 + ty + 16 * i;
        S[i]    = xnorm[n];
        xrow[i] = x + (size_t)n * D;
    }

    for (int kc = 0; kc < NCHUNK; ++kc) {
        const int k0 = kc * TN;

        __syncthreads();   // protect cs from previous iteration's readers
        {   // stage 64 codebook rows: coalesced 16B global reads
            const int col4 = tid & 63;
            const int row  = tid >> 6;
            #pragma unroll
            for (int r = 0; r < 16; ++r) {
                const int rr = row + 4 * r;
                float4 v = *(const float4*)(cb + (size_t)(k0 + rr) * D + col4 * 4);
                *(float4*)(cs + rr * CS_STRIDE + col4 * 4) = v;
            }
        }
        __syncthreads();

        float acc[4][4];
        #pragma unroll
        for (int i = 0; i < 4; ++i)
            #pragma unroll
            for (int j = 0; j < 4; ++j) acc[i][j] = 0.f;

        // Sequential fp32 FMA chain per (i,j), d ascending — replicates the
        // sgemm microkernel accumulation (single accumulator over k, FMA each
        // step). Do NOT split accumulators or reorder.
        #pragma unroll 2
        for (int dd = 0; dd < D; dd += 4) {
            float4 a[4], b[4];
            #pragma unroll
            for (int i = 0; i < 4; ++i) a[i] = *(const float4*)(xrow[i] + dd);
            #pragma unroll
            for (int j = 0; j < 4; ++j) b[j] = *(const float4*)(cs + (tx + 16 * j) * CS_STRIDE + dd);
            #pragma unroll
            for (int i = 0; i < 4; ++i)
                #pragma unroll
                for (int j = 0; j < 4; ++j) {
                    acc[i][j] += a[i].x * b[j].x;
                    acc[i][j] += a[i].y * b[j].y;
                    acc[i][j] += a[i].z * b[j].z;
                    acc[i][j] += a[i].w * b[j].w;
                }
        }

        // np-replica fp32 distance: q = (S - 2*acc) + cn, two fp32 roundings.
        // Ascending j/kc == ascending k; strict < keeps first index on ties.
        #pragma unroll
        for (int j = 0; j < 4; ++j) {
            const int k = k0 + tx + 16 * j;
            const float cn = cnorm[k];
            #pragma unroll
            for (int i = 0; i < 4; ++i) {
                const float t = S[i] - 2.0f * acc[i][j];   // one rounding (2*acc exact)
                const float q = t + cn;                    // second rounding
                if (q < runmin[i]) { runmin[i] = q; runidx[i] = k; }
            }
        }
    }

    // cross-thread argmin merge per n-row (16 tx candidates each), index tie-break
    __syncthreads();
    #pragma unroll
    for (int i = 0; i < 4; ++i) {
        const int row = ty + 16 * i;
        red_val[row * 16 + tx] = runmin[i];
        red_idx[row * 16 + tx] = runidx[i];
    }
    __syncthreads();
    if (tid < TM) {
        const int row = tid;
        float bv = red_val[row * 16];
        int   bi = red_idx[row * 16];
        #pragma unroll
        for (int t = 1; t < 16; ++t) {
            const float v = red_val[row * 16 + t];
            const int  ix = red_idx[row * 16 + t];
            if (v < bv || (v == bv && ix < bi)) { bv = v; bi = ix; }
        }
        best_idx[row] = bi;
    }
    __syncthreads();

    {   // gather winning codebook rows -> out, coalesced 16B stores
        const int col4 = tid & 63;
        const int row  = tid >> 6;
        #pragma unroll
        for (int r = 0; r < 16; ++r) {
            const int rr = row + 4 * r;
            const int k  = best_idx[rr];
            float4 v = *(const float4*)(cb + (size_t)k * D + col4 * 4);
            *(float4*)(out + (size_t)(n0 + rr) * D + col4 * 4) = v;
        }
    }
}

extern "C" void kernel_launch(void* const* d_in, const int* in_sizes, int n_in,
                              void* d_out, int out_size, void* d_ws, size_t ws_size,
                              hipStream_t stream) {
    const float* x  = (const float*)d_in[0];   // [32768, 256]
    const float* cb = (const float*)d_in[1];   // [1024, 256]
    float* out = (float*)d_out;                // [32768, 256]

    // workspace: xnorm [32768 fp32] | cnorm [1024 fp32]  (132 KB)
    float* xnorm = (float*)d_ws;
    float* cnorm = xnorm + N_ROWS;

    norms_kernel<<<(N_ROWS + K_TOTAL) / 4, 256, 0, stream>>>(x, cb, xnorm, cnorm);
    vq_kernel<<<N_ROWS / TM, 256, 0, stream>>>(x, cb, xnorm, cnorm, out);
}